// Round 1
// baseline (216.941 us; speedup 1.0000x reference)
//
#include <hip/hip_runtime.h>
#include <hip/hip_bf16.h>
#include <math.h>

#define NN 8192
#define NFEAT 1433
#define NHID 64
#define NCLASS 7
#define CAP 96

// ---------------------------------------------------------------------------
// K1: stream sub_adj once (float4), build per-row CSR of nonzeros with
// val = sigmoid(P_symm[i][j]) * adj[i][j], and compute dinv = 1/sqrt(rowsum+1).
// One wave per row, 4 waves per block.
// ---------------------------------------------------------------------------
__global__ __launch_bounds__(256) void k_build(const float* __restrict__ adj,
                                               const float* __restrict__ P,
                                               float* __restrict__ dinv,
                                               int* __restrict__ cnt,
                                               int* __restrict__ cols,
                                               float* __restrict__ vals) {
    const int wave = threadIdx.x >> 6;
    const int lane = threadIdx.x & 63;
    const int row  = blockIdx.x * 4 + wave;
    if (row >= NN) return;

    const float4* arow4 = (const float4*)(adj + (size_t)row * NN);
    const long tb = (long)row * (row + 1) / 2;
    const unsigned long long lt = (1ull << lane) - 1ull;
    const size_t rowCAP = (size_t)row * CAP;

    int base = 0;
    float dsum = 0.f;

    #pragma unroll 2
    for (int it = 0; it < NN / 256; ++it) {   // 32 iterations
        float4 a4 = arow4[it * 64 + lane];
        int jb = (it * 64 + lane) * 4;
        float av[4] = {a4.x, a4.y, a4.z, a4.w};
        #pragma unroll
        for (int s = 0; s < 4; ++s) {
            bool nz = (av[s] != 0.f);
            unsigned long long mask = __ballot(nz);
            if (nz) {
                int j = jb + s;
                long pidx = (j <= row) ? (tb + j) : ((long)j * (j + 1) / 2 + row);
                float p = P[pidx];
                float v = av[s] / (1.f + __expf(-p));   // sigmoid(p)*adj
                int pos = base + __popcll(mask & lt);
                if (pos < CAP) {
                    cols[rowCAP + pos] = j;
                    vals[rowCAP + pos] = v;
                }
                dsum += v;
            }
            base += __popcll(mask);
        }
    }
    // wave-reduce dsum
    #pragma unroll
    for (int s = 32; s; s >>= 1) dsum += __shfl_xor(dsum, s, 64);
    if (lane == 0) {
        cnt[row]  = (base < CAP) ? base : CAP;
        dinv[row] = 1.f / sqrtf(1.f + dsum);   // diag contributes 1; d > 0 always
    }
}

// ---------------------------------------------------------------------------
// K2: XW1 = x @ W1  (8192x1433 @ 1433x64), f32 vector ALU, LDS-tiled.
// Block = 256 threads computes a 32x64 output tile; 256 blocks.
// ---------------------------------------------------------------------------
#define KT 32
__global__ __launch_bounds__(256) void k_xw1(const float* __restrict__ x,
                                             const float* __restrict__ W1,
                                             float* __restrict__ XW1) {
    __shared__ float xs[KT][36];   // xs[kk][r], padded to avoid conflicts, 16B-aligned rows
    __shared__ float ws[KT][64];   // ws[kk][c]
    const int t  = threadIdx.x;
    const int m0 = blockIdx.x * 32;
    const int r0 = (t & 7) * 4;    // 4 rows
    const int c0 = (t >> 3) * 2;   // 2 cols
    float acc[4][2] = {};

    for (int k0 = 0; k0 < NFEAT; k0 += KT) {
        // x tile: 32 rows x 32 k -> xs[kk][r]
        #pragma unroll
        for (int i = 0; i < 4; ++i) {
            int e = t + 256 * i;
            int r = e >> 5, kk = e & 31;
            int k = k0 + kk;
            xs[kk][r] = (k < NFEAT) ? x[(size_t)(m0 + r) * NFEAT + k] : 0.f;
        }
        // W tile: 32 k x 64 c via float4
        {
            int kk = t >> 4, c4 = (t & 15) * 4;
            #pragma unroll
            for (int i = 0; i < 2; ++i) {
                int kkk = kk + 16 * i;
                int k = k0 + kkk;
                float4 w = (k < NFEAT) ? *(const float4*)(W1 + (size_t)k * 64 + c4)
                                       : make_float4(0.f, 0.f, 0.f, 0.f);
                *(float4*)(&ws[kkk][c4]) = w;
            }
        }
        __syncthreads();
        #pragma unroll
        for (int kk = 0; kk < KT; ++kk) {
            float4 a = *(const float4*)(&xs[kk][r0]);
            float2 b = *(const float2*)(&ws[kk][c0]);
            acc[0][0] += a.x * b.x; acc[0][1] += a.x * b.y;
            acc[1][0] += a.y * b.x; acc[1][1] += a.y * b.y;
            acc[2][0] += a.z * b.x; acc[2][1] += a.z * b.y;
            acc[3][0] += a.w * b.x; acc[3][1] += a.w * b.y;
        }
        __syncthreads();
    }
    #pragma unroll
    for (int i = 0; i < 4; ++i)
        #pragma unroll
        for (int j = 0; j < 2; ++j)
            XW1[(size_t)(m0 + r0 + i) * 64 + c0 + j] = acc[i][j];
}

// ---------------------------------------------------------------------------
// K3: h1 = relu(dinv_i * (sum_j val_ij*dinv_j*XW1[j,:] + dinv_i*XW1[i,:]) + b1)
// then fused HW2[i,:] = h1 @ W2 via shfl reduction. One wave per row.
// ---------------------------------------------------------------------------
__global__ __launch_bounds__(256) void k_spmm1(const float* __restrict__ XW1,
                                               const float* __restrict__ dinv,
                                               const int* __restrict__ cnt,
                                               const int* __restrict__ cols,
                                               const float* __restrict__ vals,
                                               const float* __restrict__ b1,
                                               const float* __restrict__ W2,
                                               float* __restrict__ HW2) {
    const int wave = threadIdx.x >> 6;
    const int lane = threadIdx.x & 63;   // hidden index
    const int row  = blockIdx.x * 4 + wave;
    if (row >= NN) return;

    const float di = dinv[row];
    float acc = di * XW1[(size_t)row * NHID + lane];   // diagonal (A_ii = 1)
    const int c = cnt[row];
    const int*   cp = cols + (size_t)row * CAP;
    const float* vp = vals + (size_t)row * CAP;
    for (int k = 0; k < c; ++k) {
        int j   = cp[k];
        float w = vp[k] * dinv[j];
        acc += w * XW1[(size_t)j * NHID + lane];
    }
    float h1 = di * acc + b1[lane];
    h1 = fmaxf(h1, 0.f);

    // h1 (lane-distributed row of 64) @ W2 (64x7) -> 7 outputs
    float o[NCLASS];
    #pragma unroll
    for (int cc = 0; cc < NCLASS; ++cc) o[cc] = h1 * W2[lane * NCLASS + cc];
    #pragma unroll
    for (int cc = 0; cc < NCLASS; ++cc)
        for (int s = 32; s; s >>= 1) o[cc] += __shfl_xor(o[cc], s, 64);
    if (lane == 0) {
        #pragma unroll
        for (int cc = 0; cc < NCLASS; ++cc)
            HW2[(size_t)row * NCLASS + cc] = o[cc];   // b2 added in K4
    }
}

// ---------------------------------------------------------------------------
// K4: h2 = norm_adj @ HW2 + b2, then log_softmax. One wave per row.
// ---------------------------------------------------------------------------
__global__ __launch_bounds__(256) void k_spmm2(const float* __restrict__ HW2,
                                               const float* __restrict__ dinv,
                                               const int* __restrict__ cnt,
                                               const int* __restrict__ cols,
                                               const float* __restrict__ vals,
                                               const float* __restrict__ b2,
                                               float* __restrict__ out) {
    const int wave = threadIdx.x >> 6;
    const int lane = threadIdx.x & 63;
    const int row  = blockIdx.x * 4 + wave;
    if (row >= NN) return;

    const int c = cnt[row];
    const int*   cp = cols + (size_t)row * CAP;
    const float* vp = vals + (size_t)row * CAP;
    float acc[NCLASS] = {};
    for (int k = lane; k < c; k += 64) {
        int j   = cp[k];
        float w = vp[k] * dinv[j];
        #pragma unroll
        for (int cc = 0; cc < NCLASS; ++cc)
            acc[cc] += w * HW2[(size_t)j * NCLASS + cc];
    }
    #pragma unroll
    for (int cc = 0; cc < NCLASS; ++cc)
        for (int s = 32; s; s >>= 1) acc[cc] += __shfl_xor(acc[cc], s, 64);

    if (lane == 0) {
        const float di = dinv[row];
        float h[NCLASS], m = -1e30f;
        #pragma unroll
        for (int cc = 0; cc < NCLASS; ++cc) {
            h[cc] = di * (acc[cc] + di * HW2[(size_t)row * NCLASS + cc]) + b2[cc];
            m = fmaxf(m, h[cc]);
        }
        float s = 0.f;
        #pragma unroll
        for (int cc = 0; cc < NCLASS; ++cc) s += expf(h[cc] - m);
        float lse = m + logf(s);
        #pragma unroll
        for (int cc = 0; cc < NCLASS; ++cc)
            out[(size_t)row * NCLASS + cc] = h[cc] - lse;
    }
}

// ---------------------------------------------------------------------------
extern "C" void kernel_launch(void* const* d_in, const int* in_sizes, int n_in,
                              void* d_out, int out_size, void* d_ws, size_t ws_size,
                              hipStream_t stream) {
    const float* x   = (const float*)d_in[0];
    const float* adj = (const float*)d_in[1];
    const float* P   = (const float*)d_in[2];
    const float* W1  = (const float*)d_in[3];
    const float* b1  = (const float*)d_in[4];
    const float* W2  = (const float*)d_in[5];
    const float* b2  = (const float*)d_in[6];
    float* out = (float*)d_out;

    char* ws = (char*)d_ws;
    const size_t SZ_DINV = (size_t)NN * 4;              // 32 KB
    const size_t SZ_CNT  = (size_t)NN * 4;              // 32 KB
    const size_t SZ_COLS = (size_t)NN * CAP * 4;        // 3 MB
    const size_t SZ_VALS = (size_t)NN * CAP * 4;        // 3 MB
    const size_t SZ_XW1  = (size_t)NN * NHID * 4;       // 2 MB

    float* dinv = (float*)ws;
    int*   cnt  = (int*)  (ws + SZ_DINV);
    int*   cols = (int*)  (ws + SZ_DINV + SZ_CNT);
    float* vals = (float*)(ws + SZ_DINV + SZ_CNT + SZ_COLS);
    float* XW1  = (float*)(ws + SZ_DINV + SZ_CNT + SZ_COLS + SZ_VALS);
    float* HW2  = (float*)(ws + SZ_DINV + SZ_CNT + SZ_COLS + SZ_VALS + SZ_XW1);

    k_build<<<dim3(NN / 4), dim3(256), 0, stream>>>(adj, P, dinv, cnt, cols, vals);
    k_xw1  <<<dim3(NN / 32), dim3(256), 0, stream>>>(x, W1, XW1);
    k_spmm1<<<dim3(NN / 4), dim3(256), 0, stream>>>(XW1, dinv, cnt, cols, vals, b1, W2, HW2);
    k_spmm2<<<dim3(NN / 4), dim3(256), 0, stream>>>(HW2, dinv, cnt, cols, vals, b2, out);
}